// Round 6
// baseline (67.210 us; speedup 1.0000x reference)
//
#include <hip/hip_runtime.h>

// L0ConjunctionLayer via log-space Taylor + MFMA, fully fused (R6):
//   out = exp(-(S1 + S2/2 + S3/3)),  Sp = matmul((Y^p)_f16, (W^p)_f16)
//   Y = 1 - x*z, z = clamp(sigmoid(qz)*1.2 - 0.1, 0, 1), t = y*w <= 0.1.
// Single kernel: fragments staged in LDS (no workspace, no second launch).
//   grid (32 m-groups, 16 n16) x 256 thr (4 waves; wave = one 16x16 C tile).
//   K = 512 processed in 2 halves of 256: stage yL (32 KB) + wL (8 KB),
//   barrier, 8 iters of [2x ds_read_b128 + 16 v_pk_mul_f16 + 3 MFMA].
//   LDS total 42 KB -> 3 blocks/CU = 12 waves/CU. Powers computed in-register.
// Fragment layouts (verified in R5, absmax 1.16e-10):
//   A[m=lane&15][k=(lane>>4)*8+j], B[k=(lane>>4)*8+j][n=lane&15],
//   C col=lane&15, row=(lane>>4)*4+i.

typedef _Float16 v8h __attribute__((ext_vector_type(8)));
typedef float v4f __attribute__((ext_vector_type(4)));

#define DIM_B 2048
#define DIM_I 512
#define DIM_O 256

__global__ __launch_bounds__(256, 3) void l0conj_fused(
    const float* __restrict__ x,    // [2048][512]
    const float* __restrict__ w,    // [512][256]
    const float* __restrict__ qz,   // [512]
    float* __restrict__ out)        // [2048][256]
{
    __shared__ float zS[DIM_I];              // 2 KB
    __shared__ _Float16 yL[4 * 8 * 512];     // 32 KB: [m16=wid][kk][lane*8+j]
    __shared__ _Float16 wL[8 * 512];         // 8 KB:  [kk][lane*8+j]

    const int t = threadIdx.x;
    const int lane = t & 63;
    const int wid = t >> 6;                  // wave 0..3 <-> m16 tile
    const int rowBase = blockIdx.x * 64;
    const int n16 = blockIdx.y;

    // z gate (fp32, lives in its own LDS region for both K-halves)
    for (int i = t; i < DIM_I; i += 256) {
        float qv = qz[i];
        float sig = 1.0f / (1.0f + __expf(-qv));
        zS[i] = fminf(fmaxf(fmaf(sig, 1.2f, -0.1f), 0.0f), 1.0f);
    }
    __syncthreads();

    v4f s1 = {0.f, 0.f, 0.f, 0.f};
    v4f s2 = {0.f, 0.f, 0.f, 0.f};
    v4f s3 = {0.f, 0.f, 0.f, 0.f};

    const int r = lane & 15, q = lane >> 4;
    const float* xp = x + (size_t)(rowBase + wid * 16 + r) * DIM_I + q * 8;

    for (int p = 0; p < 2; ++p) {
        // ---- stage Y fragments for k32 in [p*8, p*8+8); wave wid -> m16=wid
#pragma unroll
        for (int kk = 0; kk < 8; ++kk) {
            const int kw = (p * 8 + kk) * 32;         // window base in k
            const float4 x0 = *(const float4*)(xp + kw);
            const float4 x1 = *(const float4*)(xp + kw + 4);
            const float4 z0 = *(const float4*)(zS + kw + q * 8);
            const float4 z1 = *(const float4*)(zS + kw + q * 8 + 4);
            v8h y;
            y[0] = (_Float16)fmaf(-x0.x, z0.x, 1.0f);
            y[1] = (_Float16)fmaf(-x0.y, z0.y, 1.0f);
            y[2] = (_Float16)fmaf(-x0.z, z0.z, 1.0f);
            y[3] = (_Float16)fmaf(-x0.w, z0.w, 1.0f);
            y[4] = (_Float16)fmaf(-x1.x, z1.x, 1.0f);
            y[5] = (_Float16)fmaf(-x1.y, z1.y, 1.0f);
            y[6] = (_Float16)fmaf(-x1.z, z1.z, 1.0f);
            y[7] = (_Float16)fmaf(-x1.w, z1.w, 1.0f);
            *(v8h*)(yL + (wid * 8 + kk) * 512 + lane * 8) = y;
        }
        // ---- stage W fragments (shared by all 4 waves; 512 v8h slots)
#pragma unroll
        for (int i = 0; i < 2; ++i) {
            const int slot = i * 256 + t;             // (kk, lane) flat
            const int kk = slot >> 6;
            const int L = slot & 63;
            const int lq = L >> 4, lc = L & 15;
            const float* wp = w + (size_t)((p * 8 + kk) * 32 + lq * 8) * DIM_O
                                + n16 * 16 + lc;
            v8h wv;
#pragma unroll
            for (int j = 0; j < 8; ++j) wv[j] = (_Float16)wp[(size_t)j * DIM_O];
            *(v8h*)(wL + slot * 8) = wv;
        }
        __syncthreads();

        // ---- MFMA loop over this K-half
        const _Float16* pA = yL + wid * 4096 + lane * 8;
        const _Float16* pB = wL + lane * 8;
#pragma unroll
        for (int kk = 0; kk < 8; ++kk) {
            const v8h a = *(const v8h*)(pA + kk * 512);
            const v8h b = *(const v8h*)(pB + kk * 512);
            const v8h a2 = a * a;
            const v8h b2 = b * b;
            const v8h a3 = a2 * a;
            const v8h b3 = b2 * b;
            s1 = __builtin_amdgcn_mfma_f32_16x16x32_f16(a, b, s1, 0, 0, 0);
            s2 = __builtin_amdgcn_mfma_f32_16x16x32_f16(a2, b2, s2, 0, 0, 0);
            s3 = __builtin_amdgcn_mfma_f32_16x16x32_f16(a3, b3, s3, 0, 0, 0);
        }
        __syncthreads();  // protect yL/wL before restage (and exit)
    }

    // ---- epilogue: C layout col=lane&15, row=(lane>>4)*4+i
    const int col = lane & 15;
    const int row4 = (lane >> 4) * 4;
    float* op = out + (size_t)(rowBase + wid * 16 + row4) * DIM_O + n16 * 16 + col;
#pragma unroll
    for (int i = 0; i < 4; ++i) {
        const float S = s1[i] + 0.5f * s2[i] + (1.0f / 3.0f) * s3[i];
        op[(size_t)i * DIM_O] = __expf(-S);
    }
}

extern "C" void kernel_launch(void* const* d_in, const int* in_sizes, int n_in,
                              void* d_out, int out_size, void* d_ws, size_t ws_size,
                              hipStream_t stream) {
    const float* x = (const float*)d_in[0];   // [2048, 512]
    const float* w = (const float*)d_in[1];   // [512, 256]
    const float* qz = (const float*)d_in[2];  // [512]
    float* out = (float*)d_out;               // [2048, 256]

    l0conj_fused<<<dim3(DIM_B / 64, DIM_O / 16), dim3(256), 0, stream>>>(x, w, qz, out);
}